// Round 9
// baseline (145.984 us; speedup 1.0000x reference)
//
#include <hip/hip_runtime.h>

// DifferentiableFK: serial 63-body hinge chain, B=131072, fp32 in/out.
// R5-R8 ledger: write-amp fix -7us; s_load constants 0; transpose+coalesce
// +12.7us; rolled loop +12us. R8 counters: WRITE 24MB (ideal), FETCH 22MB,
// HBM 10%, LDS-conflict negligible, VALUBusy 28%, Occupancy 18%.
// Diagnosis: B/64 = 2048 waves = 2/SIMD structurally; each wave idle ~86%
// on per-iteration fixed latencies (constant fetch, trans, branches) with
// nothing to hide them. R9: amortize instead of relocate —
//  (1) 2 batch elements per thread (pair t, t+nb/2): per-iteration overhead
//      shared 2x, ILP 2x;
//  (2) hinge constants staged once to LDS, then a 2-hinge-per-trip register
//      double-buffer: next trip's ds_read_b128 x8 (broadcast) + angle loads
//      issued before current trip's ~720cy of VALU -> latency hidden;
//  (3) LDS output staging + coalesced float4 copy-out kept (two regions).

#define NBODY  63
#define NHINGE 61
#define NSITES 16
#define QDIM   68   // 7 + NHINGE
#define NT     128  // threads per block
#define LSTRIDE 49  // 48 floats/thread + 1 pad: 2-way bank max (free, m136)
#define INV2PI 0.15915494309189535f

typedef unsigned int u32;

// ws float-index layout
#define HC_OFF   0                        // [61][16]: u.wxyz, v.wxyz, a.xyz+pad, j.xyz+pad
#define SP_OFF   (NHINGE * 16)            // 976: [16][4] site_pos
#define MASK_OFF (SP_OFF + NSITES * 4)    // 1040: int[63] per-body site bitmask
#define BM_OFF   (MASK_OFF + 64)          // 1104: 2 x u32 body bitmask

// 2-element pack (element A, element B). Own struct: no operator clash with
// HIP vector types; LLVM keeps the 2 lanes as independent ILP (or pk-math).
struct P { float a, b; };
__device__ __forceinline__ P mk(float x, float y) { P r; r.a = x; r.b = y; return r; }
__device__ __forceinline__ P bc(float x) { return mk(x, x); }
__device__ __forceinline__ P operator+(P u, P v) { return mk(u.a + v.a, u.b + v.b); }
__device__ __forceinline__ P operator-(P u, P v) { return mk(u.a - v.a, u.b - v.b); }
__device__ __forceinline__ P operator*(P u, P v) { return mk(u.a * v.a, u.b * v.b); }
__device__ __forceinline__ P operator*(P u, float s) { return mk(u.a * s, u.b * s); }

__global__ void fk_setup(const float* __restrict__ body_pos, const float* __restrict__ body_quat,
                         const float* __restrict__ hinge_axis, const float* __restrict__ jnt_pos,
                         const float* __restrict__ site_pos, const int* __restrict__ site_body,
                         float* __restrict__ ws)
{
    int tid = threadIdx.x;
    if (tid < NHINGE) {
        int h = tid, bid = h + 2;
        float uw = body_quat[bid*4+0], ux = body_quat[bid*4+1];
        float uy = body_quat[bid*4+2], uz = body_quat[bid*4+3];
        float ax = hinge_axis[h*3+0], ay = hinge_axis[h*3+1], az = hinge_axis[h*3+2];
        float jx = jnt_pos[h*3+0],   jy = jnt_pos[h*3+1],   jz = jnt_pos[h*3+2];
        float bx = body_pos[bid*3+0], by = body_pos[bid*3+1], bz = body_pos[bid*3+2];
        float* o = ws + HC_OFF + h * 16;
        o[0] = uw; o[1] = ux; o[2] = uy; o[3] = uz;
        // v = body_quat (x) (0, axis)  -> local = cos*u + sin*v
        o[4] = -(ux * ax + uy * ay + uz * az);
        o[5] =  uw * ax + uy * az - uz * ay;
        o[6] =  uw * ay - ux * az + uz * ax;
        o[7] =  uw * az + ux * ay - uy * ax;
        o[8] = bx + jx; o[9] = by + jy; o[10] = bz + jz; o[11] = 0.f;
        o[12] = jx; o[13] = jy; o[14] = jz; o[15] = 0.f;
    }
    if (tid < NSITES) {
        float* o = ws + SP_OFF + tid * 4;
        o[0] = site_pos[tid*3+0];
        o[1] = site_pos[tid*3+1];
        o[2] = site_pos[tid*3+2];
        o[3] = 0.f;
    }
    if (tid == 0) {
        int* im = (int*)(ws + MASK_OFF);
        unsigned long long bm = 0ull;
        for (int b = 0; b < NBODY; b++) {
            int m = 0;
            for (int s = 0; s < NSITES; s++)
                if (site_body[s] == b) m |= (1 << s);
            im[b] = m;
            if (m) bm |= (1ull << b);
        }
        u32* pbm = (u32*)(ws + BM_OFF);
        pbm[0] = (u32)bm; pbm[1] = (u32)(bm >> 32);
    }
}

// Grid: (nb/2)/NT blocks, no guard (nb = 131072, nb/2 = 65536 = 512*128).
__global__ __launch_bounds__(NT, 1)
void fk_main(const float* __restrict__ qpos, const float* __restrict__ ws,
             float* __restrict__ out, int nb)
{
    __shared__ float sbuf[2 * NT * LSTRIDE];   // 50176 B output staging (A half, B half)
    __shared__ float cbuf[NHINGE * 16];        // 3904 B hinge constants
    const int tid = threadIdx.x;
    const int tA = blockIdx.x * NT + tid;
    const int tB = tA + (nb >> 1);
    float* myA = sbuf + tid * LSTRIDE;
    float* myB = sbuf + (NT + tid) * LSTRIDE;

    // one-time stage of hinge constants into LDS
    for (int k = tid; k < NHINGE * 16; k += NT) cbuf[k] = ws[HC_OFF + k];
    __syncthreads();

    const float* rowA = qpos + (size_t)tA * QDIM;
    const float* rowB = qpos + (size_t)tB * QDIM;

    // wave-uniform scalars (s_load, warm K$)
    const u32* pbm = (const u32*)(ws + BM_OFF);
    unsigned long long bodymask = ((unsigned long long)pbm[1] << 32) | (unsigned long long)pbm[0];
    const int* im = (const int*)(ws + MASK_OFF);

    // ---- root state (both elements) ----
    float4 ra = *reinterpret_cast<const float4*>(rowA);
    float2 rb = *reinterpret_cast<const float2*>(rowA + 4);
    float  rc = rowA[6];
    float4 sa = *reinterpret_cast<const float4*>(rowB);
    float2 sb = *reinterpret_cast<const float2*>(rowB + 4);
    float  sc = rowB[6];
    P wpx = mk(ra.x, sa.x), wpy = mk(ra.y, sa.y), wpz = mk(ra.z, sa.z);
    P qw = mk(ra.w, sa.w), qx = mk(rb.x, sb.x), qy = mk(rb.y, sb.y), qz = mk(rc, sc);
    P n2 = qw*qw + qx*qx + qy*qy + qz*qz;
    P inv = mk(rsqrtf(n2.a), rsqrtf(n2.b));
    qw = qw*inv; qx = qx*inv; qy = qy*inv; qz = qz*inv;

    auto emit = [&](int bid) {
        int m = im[bid];          // wave-uniform
        while (m) {
            int s = __ffs(m) - 1; m &= m - 1;
            const float* sp = ws + SP_OFF + s * 4;   // uniform -> s_load
            float vx = sp[0], vy = sp[1], vz = sp[2];
            P tx = (qy*bc(vz) - qz*bc(vy)) * 2.f;
            P ty = (qz*bc(vx) - qx*bc(vz)) * 2.f;
            P tz = (qx*bc(vy) - qy*bc(vx)) * 2.f;
            P ox = wpx + bc(vx) + qw*tx + (qy*tz - qz*ty);
            P oy = wpy + bc(vy) + qw*ty + (qz*tx - qx*tz);
            P oz = wpz + bc(vz) + qw*tz + (qx*ty - qy*tx);
            float* oA = myA + s * 3;
            float* oB = myB + s * 3;
            oA[0] = ox.a; oA[1] = oy.a; oA[2] = oz.a;
            oB[0] = ox.b; oB[1] = oy.b; oB[2] = oz.b;
        }
    };

    if (bodymask & 2ull) emit(1);

    auto step = [&](int h, const float4& c0, const float4& c1,
                    const float4& c2, const float4& c3, P ang) {
        P rev = ang * (0.5f * INV2PI);
        P sn = mk(__builtin_amdgcn_sinf(rev.a), __builtin_amdgcn_sinf(rev.b));
        P cs = mk(__builtin_amdgcn_cosf(rev.a), __builtin_amdgcn_cosf(rev.b));
        // local = cs*u + sn*v
        P lw = cs*bc(c0.x) + sn*bc(c1.x);
        P lx = cs*bc(c0.y) + sn*bc(c1.y);
        P ly = cs*bc(c0.z) + sn*bc(c1.z);
        P lz = cs*bc(c0.w) + sn*bc(c1.w);
        // anchor = wp + qrot(wq, a)
        float ax = c2.x, ay = c2.y, az = c2.z;
        P tx = (qy*bc(az) - qz*bc(ay)) * 2.f;
        P ty = (qz*bc(ax) - qx*bc(az)) * 2.f;
        P tz = (qx*bc(ay) - qy*bc(ax)) * 2.f;
        P anx = wpx + bc(ax) + qw*tx + (qy*tz - qz*ty);
        P any_= wpy + bc(ay) + qw*ty + (qz*tx - qx*tz);
        P anz = wpz + bc(az) + qw*tz + (qx*ty - qy*tx);
        // nq = qmul(wq, local)
        P nw = qw*lw - qx*lx - qy*ly - qz*lz;
        P nx = qw*lx + qx*lw + qy*lz - qz*ly;
        P ny = qw*ly - qx*lz + qy*lw + qz*lx;
        P nz = qw*lz + qx*ly - qy*lx + qz*lw;
        // wp = anchor - qrot(nq, j)
        float jx = c3.x, jy = c3.y, jz = c3.z;
        P t2x = (ny*bc(jz) - nz*bc(jy)) * 2.f;
        P t2y = (nz*bc(jx) - nx*bc(jz)) * 2.f;
        P t2z = (nx*bc(jy) - ny*bc(jx)) * 2.f;
        wpx = anx - (bc(jx) + nw*t2x + (ny*t2z - nz*t2y));
        wpy = any_ - (bc(jy) + nw*t2y + (nz*t2x - nx*t2z));
        wpz = anz - (bc(jz) + nw*t2z + (nx*t2y - ny*t2x));
        qw = nw; qx = nx; qy = ny; qz = nz;
        if ((bodymask >> (h + 2)) & 1ull) emit(h + 2);
    };

    auto ldc = [&](int h, float4& d0, float4& d1, float4& d2, float4& d3) {
        const float4* p = reinterpret_cast<const float4*>(cbuf + h * 16);
        d0 = p[0]; d1 = p[1]; d2 = p[2]; d3 = p[3];   // ds_read_b128 x4, broadcast
    };

    // ---- software-pipelined chain: 2 hinges/trip, constants double-buffered ----
    float4 ea0, ea1, ea2, ea3, eb0, eb1, eb2, eb3;
    ldc(0, ea0, ea1, ea2, ea3);
    ldc(1, eb0, eb1, eb2, eb3);
    P angE = mk(rowA[7], rowB[7]);
    P angO = mk(rowA[8], rowB[8]);

#pragma unroll 1
    for (int h = 0; h < 60; h += 2) {
        int h2 = h + 2;
        int h3 = (h + 3 < NHINGE) ? (h + 3) : (NHINGE - 1);
        float4 na0, na1, na2, na3, nb0, nb1, nb2, nb3;
        ldc(h2, na0, na1, na2, na3);        // next trip's constants: issue now,
        ldc(h3, nb0, nb1, nb2, nb3);        // consumed ~720cy later
        P nAngE = mk(rowA[7 + h2], rowB[7 + h2]);
        P nAngO = mk(rowA[7 + h3], rowB[7 + h3]);

        step(h,     ea0, ea1, ea2, ea3, angE);
        step(h + 1, eb0, eb1, eb2, eb3, angO);

        ea0 = na0; ea1 = na1; ea2 = na2; ea3 = na3;
        eb0 = nb0; eb1 = nb1; eb2 = nb2; eb3 = nb3;
        angE = nAngE; angO = nAngO;
    }
    step(60, ea0, ea1, ea2, ea3, angE);     // last hinge (61 is odd)

    __syncthreads();

    // ---- coalesced copy-out: two regions of NT*48 floats = 24 KiB each ----
    {
        size_t baseA = (size_t)(blockIdx.x * NT) * 48;
        size_t baseB = baseA + (size_t)(nb >> 1) * 48;
        float4* outA = reinterpret_cast<float4*>(out + baseA);
        float4* outB = reinterpret_cast<float4*>(out + baseB);
#pragma unroll
        for (int k = 0; k < 12; k++) {
            int g = k * NT + tid;
            int q = g / 12;
            int r = (g - q * 12) * 4;
            const float* pA = sbuf + q * LSTRIDE + r;
            const float* pB = sbuf + (NT + q) * LSTRIDE + r;
            float4 vA = { pA[0], pA[1], pA[2], pA[3] };
            float4 vB = { pB[0], pB[1], pB[2], pB[3] };
            outA[g] = vA;   // 64 lanes x 16B contiguous = 1 KiB/instr
            outB[g] = vB;
        }
    }
}

extern "C" void kernel_launch(void* const* d_in, const int* in_sizes, int n_in,
                              void* d_out, int out_size, void* d_ws, size_t ws_size,
                              hipStream_t stream)
{
    const float* qpos       = (const float*)d_in[0];
    const float* body_pos   = (const float*)d_in[1];
    const float* body_quat  = (const float*)d_in[2];
    const float* hinge_axis = (const float*)d_in[3];
    const float* jnt_pos    = (const float*)d_in[4];
    const float* site_pos   = (const float*)d_in[5];
    // d_in[6] = body_parent: max(arange-1,0) -> serial chain, unused
    const int* site_body    = (const int*)d_in[7];
    float* ws = (float*)d_ws;

    int nb = in_sizes[0] / QDIM;   // 131072; nb/2 = 65536 = 512*128 (exact)

    fk_setup<<<1, 64, 0, stream>>>(body_pos, body_quat, hinge_axis, jnt_pos,
                                   site_pos, site_body, ws);
    fk_main<<<(nb / 2) / NT, NT, 0, stream>>>(qpos, ws, (float*)d_out, nb);
}

// Round 10
// 137.418 us; speedup vs baseline: 1.0623x; 1.0623x over previous
//
#include <hip/hip_runtime.h>

// DifferentiableFK: serial 63-body hinge chain, B=131072, fp32 in/out.
// R5-R9: every operand-placement/occupancy tweak left fk_main at 43-56us,
// VALUBusy ~30% => ~1700cy unhidden stall per serial hinge iteration, with
// TLP structurally capped at 2 waves/SIMD (B/64=2048 waves).
// R10: SEGMENTED SCAN. Hinge step is a rigid transform compose:
//   L_h = (local_q, t_h = a - qrot(local_q, j)),  world = Root∘L0∘...∘L59
// (associative). 4 lanes per element: lane k composes hinges [16k,16k+len)
// serially (len=16,16,16,13), recording each site in segment-local coords to
// LDS staging when passing its body; 2-step shuffle scan gives each lane its
// global prefix P_k; lane applies P_k to its recorded sites in-place; then
// coalesced float4 copy-out. Serial latency chain 61->16 iters AND waves
// 2048->8192 (8/SIMD).

#define NBODY  63
#define NHINGE 61
#define NSITES 16
#define QDIM   68   // 7 + NHINGE
#define NT     256
#define EPB    64   // elements per block (NT/4)
#define EST    52   // staging stride (48 floats + 4 pad, keeps 16B alignment)
#define INV2PI 0.15915494309189535f

typedef unsigned int u32;

// ws float-index layout (setup kernel writes, fk_main stages to LDS)
#define HC_OFF   0                        // [61][16]: u.wxyz, v.wxyz, a.xyz+pad, j.xyz+pad
#define SP_OFF   (NHINGE * 16)            // 976: [16][4] site_pos
#define MASK_OFF (SP_OFF + NSITES * 4)    // 1040: int[63] per-body site bitmask
#define BM_OFF   (MASK_OFF + 64)          // 1104: 2 x u32 body bitmask (unused in R10)

struct X { float qw, qx, qy, qz, tx, ty, tz; };   // rigid transform (quat, trans)

// C(A,B): apply B first, then A.  (qmul(Aq,Bq), qrot(Aq,Bt)+At)
__device__ __forceinline__ X xcompose(const X& A, const X& B) {
    X r;
    r.qw = A.qw*B.qw - A.qx*B.qx - A.qy*B.qy - A.qz*B.qz;
    r.qx = A.qw*B.qx + A.qx*B.qw + A.qy*B.qz - A.qz*B.qy;
    r.qy = A.qw*B.qy - A.qx*B.qz + A.qy*B.qw + A.qz*B.qx;
    r.qz = A.qw*B.qz + A.qx*B.qy - A.qy*B.qx + A.qz*B.qw;
    float cx = 2.f*(A.qy*B.tz - A.qz*B.ty);
    float cy = 2.f*(A.qz*B.tx - A.qx*B.tz);
    float cz = 2.f*(A.qx*B.ty - A.qy*B.tx);
    r.tx = B.tx + A.qw*cx + (A.qy*cz - A.qz*cy) + A.tx;
    r.ty = B.ty + A.qw*cy + (A.qz*cx - A.qx*cz) + A.ty;
    r.tz = B.tz + A.qw*cz + (A.qx*cy - A.qy*cx) + A.tz;
    return r;
}

__global__ void fk_setup(const float* __restrict__ body_pos, const float* __restrict__ body_quat,
                         const float* __restrict__ hinge_axis, const float* __restrict__ jnt_pos,
                         const float* __restrict__ site_pos, const int* __restrict__ site_body,
                         float* __restrict__ ws)
{
    int tid = threadIdx.x;
    if (tid < NHINGE) {
        int h = tid, bid = h + 2;
        float uw = body_quat[bid*4+0], ux = body_quat[bid*4+1];
        float uy = body_quat[bid*4+2], uz = body_quat[bid*4+3];
        float ax = hinge_axis[h*3+0], ay = hinge_axis[h*3+1], az = hinge_axis[h*3+2];
        float jx = jnt_pos[h*3+0],   jy = jnt_pos[h*3+1],   jz = jnt_pos[h*3+2];
        float bx = body_pos[bid*3+0], by = body_pos[bid*3+1], bz = body_pos[bid*3+2];
        float* o = ws + HC_OFF + h * 16;
        o[0] = uw; o[1] = ux; o[2] = uy; o[3] = uz;
        // v = body_quat (x) (0, axis)  -> local = cos*u + sin*v
        o[4] = -(ux * ax + uy * ay + uz * az);
        o[5] =  uw * ax + uy * az - uz * ay;
        o[6] =  uw * ay - ux * az + uz * ax;
        o[7] =  uw * az + ux * ay - uy * ax;
        o[8] = bx + jx; o[9] = by + jy; o[10] = bz + jz; o[11] = 0.f;
        o[12] = jx; o[13] = jy; o[14] = jz; o[15] = 0.f;
    }
    if (tid < NSITES) {
        float* o = ws + SP_OFF + tid * 4;
        o[0] = site_pos[tid*3+0];
        o[1] = site_pos[tid*3+1];
        o[2] = site_pos[tid*3+2];
        o[3] = 0.f;
    }
    if (tid == 0) {
        int* im = (int*)(ws + MASK_OFF);
        unsigned long long bm = 0ull;
        for (int b = 0; b < NBODY; b++) {
            int m = 0;
            for (int s = 0; s < NSITES; s++)
                if (site_body[s] == b) m |= (1 << s);
            im[b] = m;
            if (m) bm |= (1ull << b);
        }
        u32* pbm = (u32*)(ws + BM_OFF);
        pbm[0] = (u32)bm; pbm[1] = (u32)(bm >> 32);
    }
}

// Grid: 2048 blocks x 256 threads; 4 lanes per element, 64 elements/block.
__global__ __launch_bounds__(NT, 4)
void fk_main(const float* __restrict__ qpos, const float* __restrict__ ws,
             float* __restrict__ out)
{
    __shared__ float cbuf[NHINGE * 16];   // 3904 B hinge constants
    __shared__ float spbuf[NSITES * 4];   //  256 B site_pos
    __shared__ int   smask[64];           //  256 B per-body site bitmask
    __shared__ float stag[EPB * EST];     // 13312 B site staging (local->world in place)

    const int tid  = threadIdx.x;
    const int lane = tid & 63;
    const int k    = tid & 3;             // segment index within element
    const int eloc = tid >> 2;            // element within block
    const int start = k * 16;             // first hinge of my segment
    const int len   = (k < 3) ? 16 : 13;  // hinges 0..60

    // ---- stage constants to LDS ----
    for (int i = tid; i < NHINGE * 16; i += NT) cbuf[i] = ws[HC_OFF + i];
    if (tid < NSITES * 4) spbuf[tid] = ws[SP_OFF + tid];
    if (tid < 63) smask[tid] = ((const int*)(ws + MASK_OFF))[tid];
    __syncthreads();

    const float* rowp = qpos + (size_t)(blockIdx.x * EPB + eloc) * QDIM;
    float* my = stag + eloc * EST;

    // ---- preload my segment's angles (predicated; no OOB) ----
    float f[16];
#pragma unroll
    for (int i = 0; i < 16; i++) { f[i] = 0.f; if (i < len) f[i] = rowp[7 + start + i]; }

    // ---- init segment state: lane 0 folds in the root transform ----
    X s = {1.f, 0.f, 0.f, 0.f, 0.f, 0.f, 0.f};
    int mysites = 0;

    auto record = [&](int m) {
        mysites |= m;
        while (m) {
            int si = __ffs(m) - 1; m &= m - 1;
            float vx = spbuf[si*4+0], vy = spbuf[si*4+1], vz = spbuf[si*4+2];
            float cx = 2.f*(s.qy*vz - s.qz*vy);
            float cy = 2.f*(s.qz*vx - s.qx*vz);
            float cz = 2.f*(s.qx*vy - s.qy*vx);
            float* o = my + si * 3;
            o[0] = vx + s.qw*cx + (s.qy*cz - s.qz*cy) + s.tx;
            o[1] = vy + s.qw*cy + (s.qz*cx - s.qx*cz) + s.ty;
            o[2] = vz + s.qw*cz + (s.qx*cy - s.qy*cx) + s.tz;
        }
    };

    if (k == 0) {
        float4 r0 = *reinterpret_cast<const float4*>(rowp);
        float2 r1 = *reinterpret_cast<const float2*>(rowp + 4);
        float  r2 = rowp[6];
        float inv = rsqrtf(r0.w*r0.w + r1.x*r1.x + r1.y*r1.y + r2*r2);
        s.qw = r0.w*inv; s.qx = r1.x*inv; s.qy = r1.y*inv; s.qz = r2*inv;
        s.tx = r0.x; s.ty = r0.y; s.tz = r0.z;
        int m1 = smask[1];
        if (m1) record(m1);               // body 1 sites (already world: P_0 = Id)
    }

    // ---- phase 1: serial compose over my 16-hinge segment ----
#pragma unroll
    for (int i = 0; i < 16; i++) {
        if (i < len) {
            int h = start + i;
            const float4* cp = reinterpret_cast<const float4*>(cbuf + h * 16);
            float4 c0 = cp[0], c1 = cp[1], c2 = cp[2], c3 = cp[3];
            float rev = f[i] * (0.5f * INV2PI);
            float sn = __builtin_amdgcn_sinf(rev);
            float cs = __builtin_amdgcn_cosf(rev);
            // local quaternion = cs*u + sn*v
            float lw = cs*c0.x + sn*c1.x;
            float lx = cs*c0.y + sn*c1.y;
            float ly = cs*c0.z + sn*c1.z;
            float lz = cs*c0.w + sn*c1.w;
            // t_h = a - qrot(local, j)
            float jx = c3.x, jy = c3.y, jz = c3.z;
            float cx = 2.f*(ly*jz - lz*jy);
            float cy = 2.f*(lz*jx - lx*jz);
            float cz = 2.f*(lx*jy - ly*jx);
            float thx = c2.x - (jx + lw*cx + (ly*cz - lz*cy));
            float thy = c2.y - (jy + lw*cy + (lz*cx - lx*cz));
            float thz = c2.z - (jz + lw*cz + (lx*cy - ly*cx));
            // s = s ∘ L_h : t += qrot(sq, th); q = qmul(sq, local)
            float dx = 2.f*(s.qy*thz - s.qz*thy);
            float dy = 2.f*(s.qz*thx - s.qx*thz);
            float dz = 2.f*(s.qx*thy - s.qy*thx);
            s.tx += thx + s.qw*dx + (s.qy*dz - s.qz*dy);
            s.ty += thy + s.qw*dy + (s.qz*dx - s.qx*dz);
            s.tz += thz + s.qw*dz + (s.qx*dy - s.qy*dx);
            float nw = s.qw*lw - s.qx*lx - s.qy*ly - s.qz*lz;
            float nx = s.qw*lx + s.qx*lw + s.qy*lz - s.qz*ly;
            float ny = s.qw*ly - s.qx*lz + s.qy*lw + s.qz*lx;
            float nz = s.qw*lz + s.qx*ly - s.qy*lx + s.qz*lw;
            s.qw = nw; s.qx = nx; s.qy = ny; s.qz = nz;
            // record sites at child body (segment-local coords)
            int m = smask[h + 2];
            if (m) record(m);
        }
    }

    // ---- phase 2: shuffle scan over the 4 segment transforms ----
    X x = s;
#pragma unroll
    for (int d = 1; d <= 2; d <<= 1) {
        int src = lane - d; if (src < 0) src = lane;   // clamped; unused when k<d
        X y;
        y.qw = __shfl(x.qw, src); y.qx = __shfl(x.qx, src);
        y.qy = __shfl(x.qy, src); y.qz = __shfl(x.qz, src);
        y.tx = __shfl(x.tx, src); y.ty = __shfl(x.ty, src); y.tz = __shfl(x.tz, src);
        if (k >= d) x = xcompose(y, x);
    }
    X P;
    {
        int src = lane - 1; if (src < 0) src = lane;
        P.qw = __shfl(x.qw, src); P.qx = __shfl(x.qx, src);
        P.qy = __shfl(x.qy, src); P.qz = __shfl(x.qz, src);
        P.tx = __shfl(x.tx, src); P.ty = __shfl(x.ty, src); P.tz = __shfl(x.tz, src);
    }

    // ---- phase 3: apply my global prefix to my recorded sites (k>0) ----
    if (k > 0) {
        int m = mysites;
        while (m) {
            int si = __ffs(m) - 1; m &= m - 1;
            float* o = my + si * 3;
            float vx = o[0], vy = o[1], vz = o[2];
            float cx = 2.f*(P.qy*vz - P.qz*vy);
            float cy = 2.f*(P.qz*vx - P.qx*vz);
            float cz = 2.f*(P.qx*vy - P.qy*vx);
            o[0] = vx + P.qw*cx + (P.qy*cz - P.qz*cy) + P.tx;
            o[1] = vy + P.qw*cy + (P.qz*cx - P.qx*cz) + P.ty;
            o[2] = vz + P.qw*cz + (P.qx*cy - P.qy*cx) + P.tz;
        }
    }

    __syncthreads();

    // ---- coalesced copy-out: 64 elements * 48 floats = 768 float4 ----
    {
        float4* out4 = reinterpret_cast<float4*>(out + (size_t)blockIdx.x * (EPB * 48));
#pragma unroll
        for (int j = 0; j < 3; j++) {
            int g = j * NT + tid;
            int q = g / 12;
            int r = (g - q * 12) * 4;
            const float* p = stag + q * EST + r;   // 16B-aligned (EST*4=208, r*4*4)
            float4 v = { p[0], p[1], p[2], p[3] };
            out4[g] = v;                            // 64 lanes x 16B = 1 KiB/instr
        }
    }
}

extern "C" void kernel_launch(void* const* d_in, const int* in_sizes, int n_in,
                              void* d_out, int out_size, void* d_ws, size_t ws_size,
                              hipStream_t stream)
{
    const float* qpos       = (const float*)d_in[0];
    const float* body_pos   = (const float*)d_in[1];
    const float* body_quat  = (const float*)d_in[2];
    const float* hinge_axis = (const float*)d_in[3];
    const float* jnt_pos    = (const float*)d_in[4];
    const float* site_pos   = (const float*)d_in[5];
    // d_in[6] = body_parent: max(arange-1,0) -> serial chain, unused
    const int* site_body    = (const int*)d_in[7];
    float* ws = (float*)d_ws;

    int nb = in_sizes[0] / QDIM;   // 131072 = 2048 * 64 (exact)

    fk_setup<<<1, 64, 0, stream>>>(body_pos, body_quat, hinge_axis, jnt_pos,
                                   site_pos, site_body, ws);
    fk_main<<<nb / EPB, NT, 0, stream>>>(qpos, ws, (float*)d_out);
}